// Round 2
// baseline (243.966 us; speedup 1.0000x reference)
//
#include <hip/hip_runtime.h>
#include <stdint.h>

// Problem constants (B,T,J,D) = (64, 2048, 128, 256)
#define Bb 64
#define Tt 2048
#define Jj 128
#define Dd 256

// R7 structure (fully fused, single dispatch):
//  - prep_all eliminated. Each block rebuilds its batch's Up' tiles directly
//    in LDS from U (U[b] is 128 KB, L2-resident across the 16 blocks/batch;
//    per-unit cost = 32 B load + 8 mul + 8 cvt vs 16 B load before -- cheap),
//    and computes s_u into LDS with a 4-lane dot+reduce. This removes:
//    the second dispatch + its launch overhead, the global prep->main
//    dependency stall, and the Up/su workspace HBM round-trip (~10 MB).
//  - d_ws completely unused.
//  - Main MFMA loop, fragment layouts, epilogue identical to R6 (verified
//    R1-R6): A-frag fp32->bf16 pack in registers, 9 B-tiles in LDS
//    (8 j-tiles + w1 column for s_h-via-MFMA), C/D col=lane&15 row=quad*4+reg.

typedef __attribute__((ext_vector_type(8))) __bf16 bf16x8;
typedef __attribute__((ext_vector_type(8))) unsigned short ushort8v;
typedef __attribute__((ext_vector_type(4))) float f32x4;

__device__ __forceinline__ unsigned short f2bf(float f) {
    unsigned int u = __builtin_bit_cast(unsigned int, f);
    u += 0x7FFFu + ((u >> 16) & 1u);
    return (unsigned short)(u >> 16);
}

__device__ __forceinline__ bf16x8 pack8(const float4& a0, const float4& a1) {
    bf16x8 r;
    r[0] = (__bf16)a0.x; r[1] = (__bf16)a0.y; r[2] = (__bf16)a0.z; r[3] = (__bf16)a0.w;
    r[4] = (__bf16)a1.x; r[5] = (__bf16)a1.y; r[6] = (__bf16)a1.z; r[7] = (__bf16)a1.w;
    return r;
}

__global__ __launch_bounds__(512, 4)
void sim_fused(const float* __restrict__ H, const float* __restrict__ U,
               const float* __restrict__ w, float* __restrict__ out) {
    __shared__ ushort8v lUp[4608];   // 72 KB: tiles j=0..8, unit (j*8+ks)*64+lane
    __shared__ float lsu[Jj];        // s_u for this batch

    const int tid   = threadIdx.x;
    const int wid   = tid >> 6;
    const int lane  = tid & 63;
    const int row16 = lane & 15;
    const int quad  = lane >> 4;

    const int b  = blockIdx.x >> 4;                      // 16 blocks per batch
    const int m0 = (blockIdx.x & 15) * 128 + wid * 16;   // this wave's 16 rows

    // Issue rolling depth-3 H prefetch first (A-fragment layout: lane holds
    // row m0+row16, k-octet quad*8, slices of 32 along k) so the HBM stream
    // overlaps the LDS-build prologue.
    const float* Hp = H + ((size_t)(b * Tt + m0 + row16)) * Dd + quad * 8;
    float4 hb0[3], hb1[3];
#pragma unroll
    for (int p = 0; p < 3; ++p) {
        hb0[p] = *(const float4*)(Hp + p * 32);
        hb1[p] = *(const float4*)(Hp + p * 32 + 4);
    }

    // ---- build Up' = bf16(U*w3) tiles (+ w1-column tile) in LDS ----
    // Unit (j*8+ks)*64+l with j=p, ks=wid, l=lane: per row the 4 quads of a
    // wave cover 128 contiguous bytes of U -> coalesced, L2-resident.
    const float* Ubase = U + (size_t)b * Jj * Dd;
    const int k0 = wid * 32 + quad * 8;
#pragma unroll
    for (int p = 0; p < 9; ++p) {
        ushort8v s;
        if (p < 8) {
            const int row = p * 16 + row16;
            const float* up = Ubase + (size_t)row * Dd + k0;
            const float* wp = w + 2 * Dd + k0;
            const float4 u0 = *(const float4*)(up);
            const float4 u1 = *(const float4*)(up + 4);
            const float4 w0 = *(const float4*)(wp);
            const float4 w1 = *(const float4*)(wp + 4);
            s[0] = f2bf(u0.x * w0.x); s[1] = f2bf(u0.y * w0.y);
            s[2] = f2bf(u0.z * w0.z); s[3] = f2bf(u0.w * w0.w);
            s[4] = f2bf(u1.x * w1.x); s[5] = f2bf(u1.y * w1.y);
            s[6] = f2bf(u1.z * w1.z); s[7] = f2bf(u1.w * w1.w);
        } else {
            // w1-column tile: B[n][k] = (n==0) ? w1[k] : 0
            const bool n0 = row16 == 0;
#pragma unroll
            for (int e = 0; e < 8; ++e)
                s[e] = n0 ? f2bf(w[k0 + e]) : (unsigned short)0;
        }
        lUp[(p * 8 + wid) * 64 + lane] = s;
    }

    // ---- s_u[j] = U[b][j][:] . w2 : 4 lanes per row, 64 MACs each ----
    {
        const int row = tid >> 2;            // 512 threads -> 128 rows
        const int c0  = (tid & 3) * 64;
        const float* up = Ubase + (size_t)row * Dd + c0;
        const float* wp = w + Dd + c0;
        float ssum = 0.f;
#pragma unroll
        for (int i = 0; i < 16; ++i) {
            const float4 u = *(const float4*)(up + i * 4);
            const float4 v = *(const float4*)(wp + i * 4);
            ssum += u.x * v.x + u.y * v.y + u.z * v.z + u.w * v.w;
        }
        ssum += __shfl_xor(ssum, 1);
        ssum += __shfl_xor(ssum, 2);
        if ((tid & 3) == 0) lsu[row] = ssum;
    }

    f32x4 acc[9];
#pragma unroll
    for (int j = 0; j < 9; ++j) acc[j] = (f32x4){0.f, 0.f, 0.f, 0.f};

    __syncthreads();

#pragma unroll
    for (int ks = 0; ks < 8; ++ks) {
        const int slot = ks % 3;           // static under full unroll
        const float4 h0 = hb0[slot];
        const float4 h1 = hb1[slot];
        if (ks < 5) {                      // static: refill the slot
            hb0[slot] = *(const float4*)(Hp + (ks + 3) * 32);
            hb1[slot] = *(const float4*)(Hp + (ks + 3) * 32 + 4);
        }

        const bf16x8 af = pack8(h0, h1);
#pragma unroll
        for (int j = 0; j < 9; ++j) {
            const bf16x8 bf = __builtin_bit_cast(bf16x8, lUp[(j * 8 + ks) * 64 + lane]);
            acc[j] = __builtin_amdgcn_mfma_f32_16x16x32_bf16(af, bf, acc[j], 0, 0, 0);
        }
    }

    // s_h for output row quad*4+rg lives in lane quad*16 (col 0) of acc[8]
    float shv[4];
#pragma unroll
    for (int rg = 0; rg < 4; ++rg)
        shv[rg] = __shfl(acc[8][rg], quad * 16);

    // epilogue: C/D layout col = lane&15, row = quad*4 + reg (verified R1-R6)
    float* outW = out + ((size_t)(b * Tt + m0)) * Jj;
#pragma unroll
    for (int j = 0; j < 8; ++j) {
        const int col = j * 16 + row16;
        const float suv = lsu[col];
#pragma unroll
        for (int rg = 0; rg < 4; ++rg)
            outW[(size_t)(quad * 4 + rg) * Jj + col] = acc[j][rg] + shv[rg] + suv;
    }
}

extern "C" void kernel_launch(void* const* d_in, const int* in_sizes, int n_in,
                              void* d_out, int out_size, void* d_ws, size_t ws_size,
                              hipStream_t stream) {
    const float* H = (const float*)d_in[0];
    const float* U = (const float*)d_in[1];
    const float* w = (const float*)d_in[2];
    float* out = (float*)d_out;
    (void)d_ws; (void)ws_size;

    sim_fused<<<Bb * 16, 512, 0, stream>>>(H, U, w, out);
}

// Round 3
// 225.730 us; speedup vs baseline: 1.0808x; 1.0808x over previous
//
#include <hip/hip_runtime.h>
#include <stdint.h>

// Problem constants (B,T,J,D) = (64, 2048, 128, 256)
#define Bb 64
#define Tt 2048
#define Jj 128
#define Dd 256

// R8 structure (R7 + latency-exposure fixes; R7 counters: 95 us, all pipes
// <10%, HBM 26% -> latency-bound, NOT BW-bound; traffic floor ~31 us):
//  - Grid 512 blocks x 256 T-rows (was 1024 x 128): exactly 2 resident
//    blocks/CU, ONE round -> one serial prologue per CU-slot instead of 4,
//    and a 16-ks main loop (2 m-tiles) with the rolling H prefetch streaming
//    continuously across the m-tile boundary.
//  - Single U pass: s_u partials computed from the SAME u0/u1 registers the
//    Up'-build loads (R7 read U[b] twice per block). w1/w2/w3 slices are
//    wave-invariant -> hoisted before the p-loop. Prologue VMEM/thread
//    drops ~56 -> 22.
//  - s_u cross-wave reduction via 4 KB LDS scratch (quad-shfl reduce ->
//    lsuP[wave][row] -> threads 0..127 sum after the barrier).
//  - Verified machinery unchanged: B-fragment unit layout (j*8+ks)*64+lane,
//    w1-column tile 8 for s_h-via-MFMA, A-frag pack8, C/D col=lane&15
//    row=quad*4+reg epilogue (verified R1-R7).

typedef __attribute__((ext_vector_type(8))) __bf16 bf16x8;
typedef __attribute__((ext_vector_type(8))) unsigned short ushort8v;
typedef __attribute__((ext_vector_type(4))) float f32x4;

__device__ __forceinline__ unsigned short f2bf(float f) {
    unsigned int u = __builtin_bit_cast(unsigned int, f);
    u += 0x7FFFu + ((u >> 16) & 1u);
    return (unsigned short)(u >> 16);
}

__device__ __forceinline__ bf16x8 pack8(const float4& a0, const float4& a1) {
    bf16x8 r;
    r[0] = (__bf16)a0.x; r[1] = (__bf16)a0.y; r[2] = (__bf16)a0.z; r[3] = (__bf16)a0.w;
    r[4] = (__bf16)a1.x; r[5] = (__bf16)a1.y; r[6] = (__bf16)a1.z; r[7] = (__bf16)a1.w;
    return r;
}

__global__ __launch_bounds__(512, 4)
void sim_fused(const float* __restrict__ H, const float* __restrict__ U,
               const float* __restrict__ w, float* __restrict__ out) {
    __shared__ ushort8v lUp[4608];     // 72 KB: tiles j=0..8, unit (j*8+ks)*64+lane
    __shared__ float    lsuP[8 * Jj];  // 4 KB: per-wave s_u partials
    __shared__ float    lsu[Jj];       // reduced s_u

    const int tid   = threadIdx.x;
    const int wid   = tid >> 6;
    const int lane  = tid & 63;
    const int row16 = lane & 15;
    const int quad  = lane >> 4;

    const int b     = blockIdx.x >> 3;             // 8 blocks per batch
    const int mbase = (blockIdx.x & 7) * 256;      // 256 rows per block

    // Kick off the HBM H stream first (A-fragment layout: lane holds row
    // mbase + mt*128 + wid*16 + row16, k-octet quad*8, slices of 32 along k;
    // flattened kk = mt*8+ks, addr = Hbase + (kk>>3)*128*Dd + (kk&7)*32).
    const float* Hbase = H + ((size_t)(b * Tt + mbase + wid * 16 + row16)) * Dd + quad * 8;
    float4 hb0[3], hb1[3];
#pragma unroll
    for (int p = 0; p < 3; ++p) {
        hb0[p] = *(const float4*)(Hbase + p * 32);
        hb1[p] = *(const float4*)(Hbase + p * 32 + 4);
    }

    // Wave-invariant w slices for this wave's k-range (ks = wid)
    const int k0 = wid * 32 + quad * 8;
    const float4 w1a = *(const float4*)(w + k0);
    const float4 w1b = *(const float4*)(w + k0 + 4);
    const float4 w2a = *(const float4*)(w + Dd + k0);
    const float4 w2b = *(const float4*)(w + Dd + k0 + 4);
    const float4 w3a = *(const float4*)(w + 2 * Dd + k0);
    const float4 w3b = *(const float4*)(w + 2 * Dd + k0 + 4);

    // ---- single U pass: build Up' tiles AND s_u partials ----
    const float* Ubase = U + (size_t)b * Jj * Dd;
    float sup[8];
#pragma unroll
    for (int p = 0; p < 8; ++p) {
        const float* up = Ubase + (size_t)(p * 16 + row16) * Dd + k0;
        const float4 u0 = *(const float4*)(up);
        const float4 u1 = *(const float4*)(up + 4);
        ushort8v s;
        s[0] = f2bf(u0.x * w3a.x); s[1] = f2bf(u0.y * w3a.y);
        s[2] = f2bf(u0.z * w3a.z); s[3] = f2bf(u0.w * w3a.w);
        s[4] = f2bf(u1.x * w3b.x); s[5] = f2bf(u1.y * w3b.y);
        s[6] = f2bf(u1.z * w3b.z); s[7] = f2bf(u1.w * w3b.w);
        lUp[(p * 8 + wid) * 64 + lane] = s;
        sup[p] = u0.x * w2a.x + u0.y * w2a.y + u0.z * w2a.z + u0.w * w2a.w
               + u1.x * w2b.x + u1.y * w2b.y + u1.z * w2b.z + u1.w * w2b.w;
    }
    {   // tile 8: w1-column, B[n][k] = (n==0) ? w1[k] : 0
        const bool n0 = row16 == 0;
        ushort8v s;
        s[0] = n0 ? f2bf(w1a.x) : (unsigned short)0;
        s[1] = n0 ? f2bf(w1a.y) : (unsigned short)0;
        s[2] = n0 ? f2bf(w1a.z) : (unsigned short)0;
        s[3] = n0 ? f2bf(w1a.w) : (unsigned short)0;
        s[4] = n0 ? f2bf(w1b.x) : (unsigned short)0;
        s[5] = n0 ? f2bf(w1b.y) : (unsigned short)0;
        s[6] = n0 ? f2bf(w1b.z) : (unsigned short)0;
        s[7] = n0 ? f2bf(w1b.w) : (unsigned short)0;
        lUp[(8 * 8 + wid) * 64 + lane] = s;
    }
    // quad-reduce s_u partials (lanes {row16, +16, +32, +48} hold the 4
    // k-sub-slices of rows p*16+row16 for this wave's 32-wide k-range)
#pragma unroll
    for (int p = 0; p < 8; ++p) {
        sup[p] += __shfl_xor(sup[p], 16);
        sup[p] += __shfl_xor(sup[p], 32);
    }
    if (quad == 0) {
#pragma unroll
        for (int p = 0; p < 8; ++p)
            lsuP[wid * Jj + p * 16 + row16] = sup[p];
    }

    f32x4 acc[9];
#pragma unroll
    for (int j = 0; j < 9; ++j) acc[j] = (f32x4){0.f, 0.f, 0.f, 0.f};

    __syncthreads();

    // cross-wave s_u reduce (needed only by the epilogue)
    if (tid < Jj) {
        float s = 0.f;
#pragma unroll
        for (int ww = 0; ww < 8; ++ww) s += lsuP[ww * Jj + tid];
        lsu[tid] = s;
    }
    __syncthreads();

    // ---- main loop: 2 m-tiles x 8 ks, continuous rolling H prefetch ----
#pragma unroll
    for (int mt = 0; mt < 2; ++mt) {
#pragma unroll
        for (int ks = 0; ks < 8; ++ks) {
            const int kk   = mt * 8 + ks;
            const int slot = kk % 3;               // static under full unroll
            const float4 h0 = hb0[slot];
            const float4 h1 = hb1[slot];
            if (kk < 13) {                         // static: refill the slot
                const float* np = Hbase + (size_t)(((kk + 3) >> 3) * 128 * Dd)
                                        + ((kk + 3) & 7) * 32;
                hb0[slot] = *(const float4*)(np);
                hb1[slot] = *(const float4*)(np + 4);
            }

            const bf16x8 af = pack8(h0, h1);
#pragma unroll
            for (int j = 0; j < 9; ++j) {
                const bf16x8 bf = __builtin_bit_cast(bf16x8, lUp[(j * 8 + ks) * 64 + lane]);
                acc[j] = __builtin_amdgcn_mfma_f32_16x16x32_bf16(af, bf, acc[j], 0, 0, 0);
            }
        }

        // epilogue for this m-tile
        // s_h for output row quad*4+rg lives in lane quad*16 (col 0) of acc[8]
        float shv[4];
#pragma unroll
        for (int rg = 0; rg < 4; ++rg)
            shv[rg] = __shfl(acc[8][rg], quad * 16);

        float* outW = out + ((size_t)(b * Tt + mbase + mt * 128 + wid * 16)) * Jj;
#pragma unroll
        for (int j = 0; j < 8; ++j) {
            const int col = j * 16 + row16;
            const float suv = lsu[col];
#pragma unroll
            for (int rg = 0; rg < 4; ++rg)
                outW[(size_t)(quad * 4 + rg) * Jj + col] = acc[j][rg] + shv[rg] + suv;
        }

        if (mt == 0) {
#pragma unroll
            for (int j = 0; j < 9; ++j) acc[j] = (f32x4){0.f, 0.f, 0.f, 0.f};
        }
    }
}

extern "C" void kernel_launch(void* const* d_in, const int* in_sizes, int n_in,
                              void* d_out, int out_size, void* d_ws, size_t ws_size,
                              hipStream_t stream) {
    const float* H = (const float*)d_in[0];
    const float* U = (const float*)d_in[1];
    const float* w = (const float*)d_in[2];
    float* out = (float*)d_out;
    (void)d_ws; (void)ws_size;

    sim_fused<<<Bb * 8, 512, 0, stream>>>(H, U, w, out);
}

// Round 5
// 223.397 us; speedup vs baseline: 1.0921x; 1.0104x over previous
//
#include <hip/hip_runtime.h>
#include <stdint.h>

// Problem constants (B,T,J,D) = (64, 2048, 128, 256)
#define Bb 64
#define Tt 2048
#define Jj 128
#define Dd 256

// R10 == R9 resubmitted verbatim (R9's bench failed with "MI355X container
// failed twice" -- infra error, no kernel signal; resubmitting unchanged to
// get an uncontaminated measurement).
//
// R9 structure (R8 + H-stream latency fixes; R8 post-mortem: kernel fell out
// of top-5 (<79 us), dur_us -18 us -> prologue theory confirmed. Remaining
// gap to the ~33 us traffic floor = main-loop H latency):
//  - Rolling H prefetch deepened 3 -> 6 slots (+48 VGPR; R8 sat at VGPR=60
//    with a 128 budget at 2 blocks/CU). Single-wave lookahead ~2400 cyc vs
//    ~900 cyc HBM latency -- covered without relying on TLP.
//  - Bijective XCD swizzle: the 8 blocks sharing batch b get o&7 == b>>3, so
//    each batch's U (128 KB) is fetched into ONE XCD's L2 instead of 8.
//  - Everything else identical to R8 (verified R1-R8): single U pass builds
//    Up' tiles + s_u partials, 9 B-tiles in LDS (8 j-tiles + w1 column for
//    s_h-via-MFMA), A-frag pack8, C/D col=lane&15 row=quad*4+reg epilogue,
//    2 m-tiles x 8 ks main loop.

typedef __attribute__((ext_vector_type(8))) __bf16 bf16x8;
typedef __attribute__((ext_vector_type(8))) unsigned short ushort8v;
typedef __attribute__((ext_vector_type(4))) float f32x4;

__device__ __forceinline__ unsigned short f2bf(float f) {
    unsigned int u = __builtin_bit_cast(unsigned int, f);
    u += 0x7FFFu + ((u >> 16) & 1u);
    return (unsigned short)(u >> 16);
}

__device__ __forceinline__ bf16x8 pack8(const float4& a0, const float4& a1) {
    bf16x8 r;
    r[0] = (__bf16)a0.x; r[1] = (__bf16)a0.y; r[2] = (__bf16)a0.z; r[3] = (__bf16)a0.w;
    r[4] = (__bf16)a1.x; r[5] = (__bf16)a1.y; r[6] = (__bf16)a1.z; r[7] = (__bf16)a1.w;
    return r;
}

__global__ __launch_bounds__(512, 4)
void sim_fused(const float* __restrict__ H, const float* __restrict__ U,
               const float* __restrict__ w, float* __restrict__ out) {
    __shared__ ushort8v lUp[4608];     // 72 KB: tiles j=0..8, unit (j*8+ks)*64+lane
    __shared__ float    lsuP[8 * Jj];  // 4 KB: per-wave s_u partials
    __shared__ float    lsu[Jj];       // reduced s_u

    const int tid   = threadIdx.x;
    const int wid   = tid >> 6;
    const int lane  = tid & 63;
    const int row16 = lane & 15;
    const int quad  = lane >> 4;

    // Bijective XCD swizzle over the 512-block grid (assumed round-robin
    // blockIdx->XCD): o&7 = b>>3, so the 8 blocks of batch b share one XCD's
    // L2 for U[b]. (b, mtile) coverage is a bijection of o in [0,512).
    const int o     = blockIdx.x;
    const int b     = (o & 7) * 8 + ((o >> 3) & 7);
    const int mbase = (o >> 6) * 256;              // 8 m-tiles of 256 rows

    // Kick off the HBM H stream first (A-fragment layout: lane holds row
    // mbase + mt*128 + wid*16 + row16, k-octet quad*8, slices of 32 along k;
    // flattened kk = mt*8+ks, addr = Hbase + (kk>>3)*128*Dd + (kk&7)*32).
    const float* Hbase = H + ((size_t)(b * Tt + mbase + wid * 16 + row16)) * Dd + quad * 8;
    float4 hb0[6], hb1[6];
#pragma unroll
    for (int p = 0; p < 6; ++p) {
        const float* np = Hbase + (size_t)((p >> 3) * 128 * Dd) + (p & 7) * 32;
        hb0[p] = *(const float4*)(np);
        hb1[p] = *(const float4*)(np + 4);
    }

    // Wave-invariant w slices for this wave's k-range (ks = wid)
    const int k0 = wid * 32 + quad * 8;
    const float4 w1a = *(const float4*)(w + k0);
    const float4 w1b = *(const float4*)(w + k0 + 4);
    const float4 w2a = *(const float4*)(w + Dd + k0);
    const float4 w2b = *(const float4*)(w + Dd + k0 + 4);
    const float4 w3a = *(const float4*)(w + 2 * Dd + k0);
    const float4 w3b = *(const float4*)(w + 2 * Dd + k0 + 4);

    // ---- single U pass: build Up' tiles AND s_u partials ----
    const float* Ubase = U + (size_t)b * Jj * Dd;
    float sup[8];
#pragma unroll
    for (int p = 0; p < 8; ++p) {
        const float* up = Ubase + (size_t)(p * 16 + row16) * Dd + k0;
        const float4 u0 = *(const float4*)(up);
        const float4 u1 = *(const float4*)(up + 4);
        ushort8v s;
        s[0] = f2bf(u0.x * w3a.x); s[1] = f2bf(u0.y * w3a.y);
        s[2] = f2bf(u0.z * w3a.z); s[3] = f2bf(u0.w * w3a.w);
        s[4] = f2bf(u1.x * w3b.x); s[5] = f2bf(u1.y * w3b.y);
        s[6] = f2bf(u1.z * w3b.z); s[7] = f2bf(u1.w * w3b.w);
        lUp[(p * 8 + wid) * 64 + lane] = s;
        sup[p] = u0.x * w2a.x + u0.y * w2a.y + u0.z * w2a.z + u0.w * w2a.w
               + u1.x * w2b.x + u1.y * w2b.y + u1.z * w2b.z + u1.w * w2b.w;
    }
    {   // tile 8: w1-column, B[n][k] = (n==0) ? w1[k] : 0
        const bool n0 = row16 == 0;
        ushort8v s;
        s[0] = n0 ? f2bf(w1a.x) : (unsigned short)0;
        s[1] = n0 ? f2bf(w1a.y) : (unsigned short)0;
        s[2] = n0 ? f2bf(w1a.z) : (unsigned short)0;
        s[3] = n0 ? f2bf(w1a.w) : (unsigned short)0;
        s[4] = n0 ? f2bf(w1b.x) : (unsigned short)0;
        s[5] = n0 ? f2bf(w1b.y) : (unsigned short)0;
        s[6] = n0 ? f2bf(w1b.z) : (unsigned short)0;
        s[7] = n0 ? f2bf(w1b.w) : (unsigned short)0;
        lUp[(8 * 8 + wid) * 64 + lane] = s;
    }
    // quad-reduce s_u partials (lanes {row16, +16, +32, +48} hold the 4
    // k-sub-slices of rows p*16+row16 for this wave's 32-wide k-range)
#pragma unroll
    for (int p = 0; p < 8; ++p) {
        sup[p] += __shfl_xor(sup[p], 16);
        sup[p] += __shfl_xor(sup[p], 32);
    }
    if (quad == 0) {
#pragma unroll
        for (int p = 0; p < 8; ++p)
            lsuP[wid * Jj + p * 16 + row16] = sup[p];
    }

    f32x4 acc[9];
#pragma unroll
    for (int j = 0; j < 9; ++j) acc[j] = (f32x4){0.f, 0.f, 0.f, 0.f};

    __syncthreads();

    // cross-wave s_u reduce (needed only by the epilogue)
    if (tid < Jj) {
        float s = 0.f;
#pragma unroll
        for (int ww = 0; ww < 8; ++ww) s += lsuP[ww * Jj + tid];
        lsu[tid] = s;
    }
    __syncthreads();

    // ---- main loop: 2 m-tiles x 8 ks, rolling depth-6 H prefetch ----
#pragma unroll
    for (int mt = 0; mt < 2; ++mt) {
#pragma unroll
        for (int ks = 0; ks < 8; ++ks) {
            const int kk   = mt * 8 + ks;
            const int slot = kk % 6;               // static under full unroll
            const float4 h0 = hb0[slot];
            const float4 h1 = hb1[slot];
            if (kk < 10) {                         // static: refill the slot
                const float* np = Hbase + (size_t)(((kk + 6) >> 3) * 128 * Dd)
                                        + ((kk + 6) & 7) * 32;
                hb0[slot] = *(const float4*)(np);
                hb1[slot] = *(const float4*)(np + 4);
            }

            const bf16x8 af = pack8(h0, h1);
#pragma unroll
            for (int j = 0; j < 9; ++j) {
                const bf16x8 bf = __builtin_bit_cast(bf16x8, lUp[(j * 8 + ks) * 64 + lane]);
                acc[j] = __builtin_amdgcn_mfma_f32_16x16x32_bf16(af, bf, acc[j], 0, 0, 0);
            }
        }

        // epilogue for this m-tile
        // s_h for output row quad*4+rg lives in lane quad*16 (col 0) of acc[8]
        float shv[4];
#pragma unroll
        for (int rg = 0; rg < 4; ++rg)
            shv[rg] = __shfl(acc[8][rg], quad * 16);

        float* outW = out + ((size_t)(b * Tt + mbase + mt * 128 + wid * 16)) * Jj;
#pragma unroll
        for (int j = 0; j < 8; ++j) {
            const int col = j * 16 + row16;
            const float suv = lsu[col];
#pragma unroll
            for (int rg = 0; rg < 4; ++rg)
                outW[(size_t)(quad * 4 + rg) * Jj + col] = acc[j][rg] + shv[rg] + suv;
        }

        if (mt == 0) {
#pragma unroll
            for (int j = 0; j < 9; ++j) acc[j] = (f32x4){0.f, 0.f, 0.f, 0.f};
        }
    }
}

extern "C" void kernel_launch(void* const* d_in, const int* in_sizes, int n_in,
                              void* d_out, int out_size, void* d_ws, size_t ws_size,
                              hipStream_t stream) {
    const float* H = (const float*)d_in[0];
    const float* U = (const float*)d_in[1];
    const float* w = (const float*)d_in[2];
    float* out = (float*)d_out;
    (void)d_ws; (void)ws_size;

    sim_fused<<<Bb * 8, 512, 0, stream>>>(H, U, w, out);
}